// Round 6
// baseline (1411.928 us; speedup 1.0000x reference)
//
#include <hip/hip_runtime.h>
#include <hip/hip_bf16.h>
#include <stdint.h>

#define TOKENS 4096
#define DDIM 1024
#define FDIM 4096
#define NEXP 8
#define BM 128
#define BN 128
#define BK2 32

typedef __attribute__((ext_vector_type(4))) float f32x4;
typedef __attribute__((ext_vector_type(8))) short short8;

__device__ __forceinline__ unsigned short f2bf(float f) {
    union { float f; uint32_t u; } v; v.f = f;
    uint32_t u = v.u;
    return (unsigned short)((u + 0x7fff + ((u >> 16) & 1)) >> 16);
}

#define BARRIER() asm volatile("s_barrier" ::: "memory")
#define WAIT_VM0() asm volatile("s_waitcnt vmcnt(0)" ::: "memory")
#define GLDS(SRC, DST) __builtin_amdgcn_global_load_lds( \
    (const __attribute__((address_space(1))) void*)(SRC), \
    (__attribute__((address_space(3))) void*)(DST), 16, 0, 0)

// ---------------- X f32 -> bf16 ----------------
__global__ __launch_bounds__(256) void cvt_x(const float* __restrict__ x,
                                             unsigned short* __restrict__ xb, int n) {
    int i = (blockIdx.x * 256 + threadIdx.x) * 8;
    if (i >= n) return;
    float4 a = *(const float4*)(x + i);
    float4 b = *(const float4*)(x + i + 4);
    short8 o;
    o[0] = f2bf(a.x); o[1] = f2bf(a.y); o[2] = f2bf(a.z); o[3] = f2bf(a.w);
    o[4] = f2bf(b.x); o[5] = f2bf(b.y); o[6] = f2bf(b.z); o[7] = f2bf(b.w);
    *(short8*)(xb + i) = o;
}

// ------------- transpose + cvt: in [E][R][C] f32 -> out [E][C][R] bf16 -------------
__global__ __launch_bounds__(256) void transpose_cvt(const float* __restrict__ in,
                                                     unsigned short* __restrict__ out,
                                                     int R, int C) {
    __shared__ float tile[32][33];
    int e = blockIdx.z;
    int r0 = blockIdx.y * 32, c0 = blockIdx.x * 32;
    const float* src = in + (size_t)e * R * C;
    unsigned short* dst = out + (size_t)e * R * C;
    int t = threadIdx.x;
    int rr = t >> 3;
    int cc = (t & 7) * 4;
    float4 v = *(const float4*)(src + (size_t)(r0 + rr) * C + c0 + cc);
    tile[rr][cc + 0] = v.x; tile[rr][cc + 1] = v.y;
    tile[rr][cc + 2] = v.z; tile[rr][cc + 3] = v.w;
    __syncthreads();
    int oc = rr;
    int orr = cc;
    ushort4 o;
    o.x = f2bf(tile[orr + 0][oc]);
    o.y = f2bf(tile[orr + 1][oc]);
    o.z = f2bf(tile[orr + 2][oc]);
    o.w = f2bf(tile[orr + 3][oc]);
    *(ushort4*)(dst + (size_t)(c0 + oc) * R + r0 + orr) = o;
}

// ---------------- router: top-2 of 8 logits, build expert lists ----------------
__global__ __launch_bounds__(256) void router(const float* __restrict__ x,
                                              const float* __restrict__ wr,
                                              int* __restrict__ cnt,
                                              int* __restrict__ list) {
    __shared__ float wl[NEXP * DDIM];
    int t = threadIdx.x;
    for (int i = t; i < NEXP * DDIM; i += 256) wl[i] = wr[i];
    __syncthreads();
    int tok = blockIdx.x * 4 + (t >> 6);
    int lane = t & 63;
    float acc[NEXP];
#pragma unroll
    for (int e = 0; e < NEXP; e++) acc[e] = 0.f;
    const float* xr = x + (size_t)tok * DDIM;
    for (int d = lane; d < DDIM; d += 64) {
        float xv = xr[d];
#pragma unroll
        for (int e = 0; e < NEXP; e++) acc[e] += xv * wl[e * DDIM + d];
    }
#pragma unroll
    for (int e = 0; e < NEXP; e++) {
#pragma unroll
        for (int off = 32; off; off >>= 1) acc[e] += __shfl_xor(acc[e], off);
    }
    if (lane == 0) {
        int e1 = 0; float v1 = acc[0];
        for (int e = 1; e < NEXP; e++) if (acc[e] > v1) { v1 = acc[e]; e1 = e; }
        int e2 = -1; float v2 = -1e30f;
        for (int e = 0; e < NEXP; e++) if (e != e1 && acc[e] > v2) { v2 = acc[e]; e2 = e; }
        int p1 = atomicAdd(&cnt[e1], 1);
        list[e1 * TOKENS + p1] = tok;
        int p2 = atomicAdd(&cnt[e2], 1);
        list[e2 * TOKENS + p2] = tok;
    }
}

// ---------------- setup: offsets, work bases, per-XCD queue bounds ----------------
__global__ void setup(const int* __restrict__ cnt, int* __restrict__ off,
                      int* __restrict__ wbA, int* __restrict__ wbB,
                      int* __restrict__ qA, int* __restrict__ qlA,
                      int* __restrict__ qB, int* __restrict__ qlB) {
    if (threadIdx.x == 0) {
        int s = 0, ta = 0, tb = 0;
        for (int e = 0; e < NEXP; e++) {
            off[e] = s; s += cnt[e];
            wbA[e] = ta; wbB[e] = tb;
            int nt = (cnt[e] + BM - 1) / BM;
            ta += nt * (FDIM / BN);
            tb += nt * (DDIM / BN);
        }
        wbA[NEXP] = ta; wbB[NEXP] = tb;
        for (int x = 0; x < 8; x++) {
            qA[x]  = (int)((long)ta * x / 8);
            qlA[x] = (int)((long)ta * (x + 1) / 8);
            qB[x]  = (int)((long)tb * x / 8);
            qlB[x] = (int)((long)tb * (x + 1) / 8);
        }
    }
}

// ---------------- persistent grouped GEMM, per-XCD queues, 4 blk/CU ----------------
// C[M,N] = A[M,K]*Wt[e][N,K]^T. BM=BN=128, BK=32, 2-slot LDS (32 KB), 4 waves 2x2.
template <bool GATHER_A, bool SILU>
__global__ __launch_bounds__(256, 4) void gemm_moe6(
    const unsigned short* __restrict__ Abase,
    const unsigned short* __restrict__ Wt,      // [E][NDIM][KD] bf16
    const int* __restrict__ cnt, const int* __restrict__ off,
    const int* __restrict__ list,
    const int* __restrict__ wbase,
    int* __restrict__ qctr, const int* __restrict__ qlim,
    unsigned short* __restrict__ Hout,          // SILU out, stride NDIM
    float* __restrict__ Yout,                   // atomic out, stride NDIM
    int KD, int NDIM) {
    __shared__ alignas(16) unsigned short As[2][BM * BK2];  // 2 x 8 KB
    __shared__ alignas(16) unsigned short Bs[2][BN * BK2];  // 2 x 8 KB
    __shared__ int wsh;

    int t = threadIdx.x;
    int lane = t & 63;
    int wid = t >> 6;
    int wm = wid >> 1, wn = wid & 1;
    int r16 = lane & 15, g = lane >> 4;

    // XCD id -> start queue (correct for any value; only affects ordering/locality)
    uint32_t xcd;
    asm volatile("s_getreg_b32 %0, hwreg(HW_REG_XCC_ID)" : "=s"(xcd));
    int myq = (int)(xcd & 7);
    int tries = 0;

    // swizzled fragment read: chunk G of ROW stored at G ^ ((ROW>>1)&3); halfword idx
#define FRAG32(TILE, ROW, G) (*(const short8*)&(TILE)[(ROW) * BK2 + ((((G) ^ (((ROW) >> 1) & 3))) << 3)])

    for (;;) {
        if (t == 0) {
            int w = -1;
            while (tries < 8) {
                w = atomicAdd(&qctr[myq], 1);
                if (w < qlim[myq]) break;
                myq = (myq + 1) & 7; ++tries; w = -1;
            }
            wsh = w;
        }
        __syncthreads();
        int w = wsh;
        if (w < 0) break;

        // ---- decode work item: expert e, by (outer), mtile (inner) ----
        int e = 0;
        while (e < NEXP - 1 && w >= wbase[e + 1]) e++;
        w -= wbase[e];
        int n_e = cnt[e];
        int ntm = (n_e + BM - 1) >> 7;
        int by = w / ntm;
        int mtile = w - by * ntm;
        int m0 = mtile * BM;
        int n0 = by * BN;
        int base = off[e];

        // ---- staging pointers: 2 A + 2 B chunks of 16 B per thread per tile ----
        const unsigned short* pA[2];
        const unsigned short* pB[2];
        int ldsOff[2];
#pragma unroll
        for (int i = 0; i < 2; i++) {
            int c = i * 256 + t;
            int row = c >> 2, p = c & 3;
            int cg = p ^ ((row >> 1) & 3);
            int arow = m0 + row; if (arow >= n_e) arow = n_e - 1;
            size_t grow = GATHER_A ? (size_t)list[e * TOKENS + arow] : (size_t)(base + arow);
            pA[i] = Abase + grow * (size_t)KD + (cg << 3);
            pB[i] = Wt + ((size_t)e * NDIM + n0 + row) * (size_t)KD + (cg << 3);
            ldsOff[i] = c * 16;
        }

        f32x4 acc[4][4];
#pragma unroll
        for (int i = 0; i < 4; i++)
#pragma unroll
            for (int j = 0; j < 4; j++) acc[i][j] = f32x4{0.f, 0.f, 0.f, 0.f};

        // ---- prologue: stage tile 0 into slot 0 ----
#pragma unroll
        for (int i = 0; i < 2; i++) { GLDS(pA[i], (char*)As[0] + ldsOff[i]); pA[i] += BK2; }
#pragma unroll
        for (int i = 0; i < 2; i++) { GLDS(pB[i], (char*)Bs[0] + ldsOff[i]); pB[i] += BK2; }
        WAIT_VM0();
        BARRIER();

        const int NT = KD / BK2;
        for (int tk = 0; tk < NT; ++tk) {
            const int cur = tk & 1;
            const unsigned short* Ac = As[cur];
            const unsigned short* Bc = Bs[cur];

            // 1) fragment reads of current tile (no outstanding GLDS -> free drain)
            short8 a0 = FRAG32(Ac, wm * 64 + 0 * 16 + r16, g);
            short8 a1 = FRAG32(Ac, wm * 64 + 1 * 16 + r16, g);
            short8 a2 = FRAG32(Ac, wm * 64 + 2 * 16 + r16, g);
            short8 a3 = FRAG32(Ac, wm * 64 + 3 * 16 + r16, g);
            short8 b0 = FRAG32(Bc, wn * 64 + 0 * 16 + r16, g);
            short8 b1 = FRAG32(Bc, wn * 64 + 1 * 16 + r16, g);
            short8 b2 = FRAG32(Bc, wn * 64 + 2 * 16 + r16, g);
            short8 b3 = FRAG32(Bc, wn * 64 + 3 * 16 + r16, g);

            // 2) issue next-tile stage (covered by MFMA below + co-resident blocks)
            if (tk + 1 < NT) {
                char* Ad = (char*)As[cur ^ 1];
                char* Bd = (char*)Bs[cur ^ 1];
#pragma unroll
                for (int i = 0; i < 2; i++) { GLDS(pA[i], Ad + ldsOff[i]); pA[i] += BK2; }
#pragma unroll
                for (int i = 0; i < 2; i++) { GLDS(pB[i], Bd + ldsOff[i]); pB[i] += BK2; }
            }

            // 3) MFMA cluster
            __builtin_amdgcn_s_setprio(1);
            acc[0][0] = __builtin_amdgcn_mfma_f32_16x16x32_bf16(a0, b0, acc[0][0], 0, 0, 0);
            acc[0][1] = __builtin_amdgcn_mfma_f32_16x16x32_bf16(a0, b1, acc[0][1], 0, 0, 0);
            acc[0][2] = __builtin_amdgcn_mfma_f32_16x16x32_bf16(a0, b2, acc[0][2], 0, 0, 0);
            acc[0][3] = __builtin_amdgcn_mfma_f32_16x16x32_bf16(a0, b3, acc[0][3], 0, 0, 0);
            acc[1][0] = __builtin_amdgcn_mfma_f32_16x16x32_bf16(a1, b0, acc[1][0], 0, 0, 0);
            acc[1][1] = __builtin_amdgcn_mfma_f32_16x16x32_bf16(a1, b1, acc[1][1], 0, 0, 0);
            acc[1][2] = __builtin_amdgcn_mfma_f32_16x16x32_bf16(a1, b2, acc[1][2], 0, 0, 0);
            acc[1][3] = __builtin_amdgcn_mfma_f32_16x16x32_bf16(a1, b3, acc[1][3], 0, 0, 0);
            acc[2][0] = __builtin_amdgcn_mfma_f32_16x16x32_bf16(a2, b0, acc[2][0], 0, 0, 0);
            acc[2][1] = __builtin_amdgcn_mfma_f32_16x16x32_bf16(a2, b1, acc[2][1], 0, 0, 0);
            acc[2][2] = __builtin_amdgcn_mfma_f32_16x16x32_bf16(a2, b2, acc[2][2], 0, 0, 0);
            acc[2][3] = __builtin_amdgcn_mfma_f32_16x16x32_bf16(a2, b3, acc[2][3], 0, 0, 0);
            acc[3][0] = __builtin_amdgcn_mfma_f32_16x16x32_bf16(a3, b0, acc[3][0], 0, 0, 0);
            acc[3][1] = __builtin_amdgcn_mfma_f32_16x16x32_bf16(a3, b1, acc[3][1], 0, 0, 0);
            acc[3][2] = __builtin_amdgcn_mfma_f32_16x16x32_bf16(a3, b2, acc[3][2], 0, 0, 0);
            acc[3][3] = __builtin_amdgcn_mfma_f32_16x16x32_bf16(a3, b3, acc[3][3], 0, 0, 0);
            __builtin_amdgcn_s_setprio(0);

            // 4) next tile resident before anyone reads it
            WAIT_VM0();
            BARRIER();
        }

        // ---- epilogue: row = m0+wm*64+mi*16+g*4+q; col = n0+wn*64+nj*16+r16 ----
#pragma unroll
        for (int mi = 0; mi < 4; ++mi) {
#pragma unroll
            for (int nj = 0; nj < 4; ++nj) {
#pragma unroll
                for (int qq = 0; qq < 4; ++qq) {
                    int lr = wm * 64 + mi * 16 + g * 4 + qq;
                    if (m0 + lr < n_e) {
                        int col = n0 + wn * 64 + nj * 16 + r16;
                        float v = acc[mi][nj][qq];
                        if (SILU) {
                            v = v / (1.f + __expf(-v));
                            Hout[(size_t)(base + m0 + lr) * NDIM + col] = f2bf(v);
                        } else {
                            int tok = list[e * TOKENS + m0 + lr];
                            atomicAdd(&Yout[(size_t)tok * NDIM + col], v);
                        }
                    }
                }
            }
        }
    }
#undef FRAG32
}

extern "C" void kernel_launch(void* const* d_in, const int* in_sizes, int n_in,
                              void* d_out, int out_size, void* d_ws, size_t ws_size,
                              hipStream_t stream) {
    const float* X  = (const float*)d_in[0];
    const float* Wr = (const float*)d_in[1];
    const float* W1 = (const float*)d_in[2];
    const float* W2 = (const float*)d_in[3];
    float* Y = (float*)d_out;

    char* ws = (char*)d_ws;
    int* cnt  = (int*)(ws + 0);
    int* off  = (int*)(ws + 64);
    int* wbA  = (int*)(ws + 128);
    int* wbB  = (int*)(ws + 192);
    int* qA   = (int*)(ws + 256);
    int* qlA  = (int*)(ws + 288);
    int* qB   = (int*)(ws + 320);
    int* qlB  = (int*)(ws + 352);
    int* list = (int*)(ws + 1024);                               // 128 KB
    unsigned short* Xb = (unsigned short*)(ws + (1ull << 20));   // 8 MB
    unsigned short* WT = (unsigned short*)(ws + (16ull << 20));  // 64 MB (W1T, then W2T)
    unsigned short* H  = (unsigned short*)(ws + (80ull << 20));  // 64 MB

    hipMemsetAsync(d_out, 0, (size_t)out_size * sizeof(float), stream);
    hipMemsetAsync(cnt, 0, 32, stream);

    cvt_x<<<TOKENS * DDIM / (256 * 8), 256, 0, stream>>>(X, Xb, TOKENS * DDIM);
    router<<<TOKENS / 4, 256, 0, stream>>>(X, Wr, cnt, list);
    setup<<<1, 64, 0, stream>>>(cnt, off, wbA, wbB, qA, qlA, qB, qlB);

    // W1 [E][D][F] -> W1T [E][F][D] bf16
    transpose_cvt<<<dim3(FDIM / 32, DDIM / 32, NEXP), 256, 0, stream>>>(W1, WT, DDIM, FDIM);
    // Pass A: H[slot][F] = silu(X[tok] @ W1[e])
    gemm_moe6<true, true><<<1024, 256, 0, stream>>>(
        Xb, WT, cnt, off, list, wbA, qA, qlA, H, nullptr, DDIM, FDIM);

    // W2 [E][F][D] -> W2T [E][D][F] bf16 (reuses WT)
    transpose_cvt<<<dim3(DDIM / 32, FDIM / 32, NEXP), 256, 0, stream>>>(W2, WT, FDIM, DDIM);
    // Pass B: Y[tok][D] += H[slot] @ W2[e]
    gemm_moe6<false, false><<<1024, 256, 0, stream>>>(
        H, WT, cnt, off, list, wbB, qB, qlB, nullptr, Y, FDIM, DDIM);
}

// Round 7
// 492.343 us; speedup vs baseline: 2.8678x; 2.8678x over previous
//
#include <hip/hip_runtime.h>
#include <hip/hip_bf16.h>
#include <stdint.h>

#define TOKENS 4096
#define DDIM 1024
#define FDIM 4096
#define NEXP 8

typedef __attribute__((ext_vector_type(4))) float f32x4;
typedef __attribute__((ext_vector_type(8))) short short8;

__device__ __forceinline__ unsigned short f2bf(float f) {
    union { float f; uint32_t u; } v; v.f = f;
    uint32_t u = v.u;
    return (unsigned short)((u + 0x7fff + ((u >> 16) & 1)) >> 16);
}

#define BARRIER() asm volatile("s_barrier" ::: "memory")
#define WAIT_VM0() asm volatile("s_waitcnt vmcnt(0)" ::: "memory")
#define WAIT_LGKM0() asm volatile("s_waitcnt lgkmcnt(0)" ::: "memory")
#define GLDS(SRC, DST) __builtin_amdgcn_global_load_lds( \
    (const __attribute__((address_space(1))) void*)(SRC), \
    (__attribute__((address_space(3))) void*)(DST), 16, 0, 0)

// opaque asm LDS read: my explicit waits control all ordering (rule #18 applied below)
__device__ __forceinline__ short8 dsr(uint32_t addr) {
    short8 d;
    asm volatile("ds_read_b128 %0, %1" : "=v"(d) : "v"(addr));
    return d;
}

// ---------------- X f32 -> bf16 ----------------
__global__ __launch_bounds__(256) void cvt_x(const float* __restrict__ x,
                                             unsigned short* __restrict__ xb, int n) {
    int i = (blockIdx.x * 256 + threadIdx.x) * 8;
    if (i >= n) return;
    float4 a = *(const float4*)(x + i);
    float4 b = *(const float4*)(x + i + 4);
    short8 o;
    o[0] = f2bf(a.x); o[1] = f2bf(a.y); o[2] = f2bf(a.z); o[3] = f2bf(a.w);
    o[4] = f2bf(b.x); o[5] = f2bf(b.y); o[6] = f2bf(b.z); o[7] = f2bf(b.w);
    *(short8*)(xb + i) = o;
}

// ------------- transpose + cvt: in [E][R][C] f32 -> out [E][C][R] bf16 -------------
__global__ __launch_bounds__(256) void transpose_cvt(const float* __restrict__ in,
                                                     unsigned short* __restrict__ out,
                                                     int R, int C) {
    __shared__ float tile[32][33];
    int e = blockIdx.z;
    int r0 = blockIdx.y * 32, c0 = blockIdx.x * 32;
    const float* src = in + (size_t)e * R * C;
    unsigned short* dst = out + (size_t)e * R * C;
    int t = threadIdx.x;
    int rr = t >> 3;
    int cc = (t & 7) * 4;
    float4 v = *(const float4*)(src + (size_t)(r0 + rr) * C + c0 + cc);
    tile[rr][cc + 0] = v.x; tile[rr][cc + 1] = v.y;
    tile[rr][cc + 2] = v.z; tile[rr][cc + 3] = v.w;
    __syncthreads();
    int oc = rr;
    int orr = cc;
    ushort4 o;
    o.x = f2bf(tile[orr + 0][oc]);
    o.y = f2bf(tile[orr + 1][oc]);
    o.z = f2bf(tile[orr + 2][oc]);
    o.w = f2bf(tile[orr + 3][oc]);
    *(ushort4*)(dst + (size_t)(c0 + oc) * R + r0 + orr) = o;
}

// ---------------- router: top-2 of 8 logits, build expert lists ----------------
__global__ __launch_bounds__(256) void router(const float* __restrict__ x,
                                              const float* __restrict__ wr,
                                              int* __restrict__ cnt,
                                              int* __restrict__ list) {
    __shared__ float wl[NEXP * DDIM];
    int t = threadIdx.x;
    for (int i = t; i < NEXP * DDIM; i += 256) wl[i] = wr[i];
    __syncthreads();
    int tok = blockIdx.x * 4 + (t >> 6);
    int lane = t & 63;
    float acc[NEXP];
#pragma unroll
    for (int e = 0; e < NEXP; e++) acc[e] = 0.f;
    const float* xr = x + (size_t)tok * DDIM;
    for (int d = lane; d < DDIM; d += 64) {
        float xv = xr[d];
#pragma unroll
        for (int e = 0; e < NEXP; e++) acc[e] += xv * wl[e * DDIM + d];
    }
#pragma unroll
    for (int e = 0; e < NEXP; e++) {
#pragma unroll
        for (int off = 32; off; off >>= 1) acc[e] += __shfl_xor(acc[e], off);
    }
    if (lane == 0) {
        int e1 = 0; float v1 = acc[0];
        for (int e = 1; e < NEXP; e++) if (acc[e] > v1) { v1 = acc[e]; e1 = e; }
        int e2 = -1; float v2 = -1e30f;
        for (int e = 0; e < NEXP; e++) if (e != e1 && acc[e] > v2) { v2 = acc[e]; e2 = e; }
        int p1 = atomicAdd(&cnt[e1], 1);
        list[e1 * TOKENS + p1] = tok;
        int p2 = atomicAdd(&cnt[e2], 1);
        list[e2 * TOKENS + p2] = tok;
    }
}

// ---------------- setup: offsets, work bases (256-row tiles), queue reset ----------------
__global__ void setup(const int* __restrict__ cnt, int* __restrict__ off,
                      int* __restrict__ wbA, int* __restrict__ wbB,
                      int* __restrict__ qctr) {
    if (threadIdx.x == 0) {
        int s = 0, ta = 0, tb = 0;
        for (int e = 0; e < NEXP; e++) {
            off[e] = s; s += cnt[e];
            wbA[e] = ta; wbB[e] = tb;
            int ntm = (cnt[e] + 255) >> 8;
            ta += ntm * 16;      // pass A: 16 n-tiles of 256
            tb += ntm * 16;      // pass B: 8 n-tiles of 128 x 2 k-chunks
        }
        wbA[NEXP] = ta; wbB[NEXP] = tb;
        qctr[0] = 0; qctr[1] = 0;
    }
}

// ---------------- persistent grouped GEMM: 256-row tile, 8 waves, 2-phase ----------------
// C[M,N] = A[M,K] * Wt[e][N,K]^T. BM=256, BN=BN_, BK=64, 512 thr (2M x 4N waves),
// double-buffered LDS, stage-first + asm ds_read + vmcnt(0)+barrier per K-tile.
template <int BN_, bool GATHER_A, bool SILU, int KSPLIT>
__global__ __launch_bounds__(512, 2) void gemm_moe7(
    const unsigned short* __restrict__ Abase,
    const unsigned short* __restrict__ Wt,      // [E][NW][KD] bf16
    const int* __restrict__ cnt, const int* __restrict__ off,
    const int* __restrict__ list,
    const int* __restrict__ wbase,              // [NEXP+1]
    int* __restrict__ qctr,
    unsigned short* __restrict__ Hout,          // SILU out, stride NW
    float* __restrict__ Yout,                   // atomic out, stride NW
    int KD, int KLEN, int NW) {
    constexpr int NF = BN_ / 64;                // B-frags per wave (4 or 2)
    constexpr int WCOL = BN_ / 4;               // cols per wave
    constexpr int NA = 4;                       // A stage chunks/thread
    constexpr int NB = BN_ * 8 / 512;           // B stage chunks/thread (4 or 2)
    constexpr uint32_t SLOTA = 256 * 64 * 2;
    constexpr uint32_t SLOTB = BN_ * 64 * 2;

    __shared__ alignas(16) unsigned short As[2][256 * 64];
    __shared__ alignas(16) unsigned short Bs[2][BN_ * 64];
    __shared__ int wsh;

    const int t = threadIdx.x;
    const int lane = t & 63;
    const int wid = t >> 6;
    const int wm = wid >> 2, wn = wid & 3;
    const int r16 = lane & 15, g = lane >> 4;
    const int total = wbase[NEXP];

    const uint32_t asB = (uint32_t)(uintptr_t)&As[0][0];
    const uint32_t bsB = (uint32_t)(uintptr_t)&Bs[0][0];
    const uint32_t swz = (uint32_t)(r16 & 7) << 4;   // row&7 == r16&7 for all frag rows
    const uint32_t g16 = (uint32_t)g << 4;
    uint32_t rA[8], rB[NF];
#pragma unroll
    for (int mi = 0; mi < 8; mi++) rA[mi] = asB + (uint32_t)(wm * 128 + mi * 16 + r16) * 128u;
#pragma unroll
    for (int nj = 0; nj < NF; nj++) rB[nj] = bsB + (uint32_t)(wn * WCOL + nj * 16 + r16) * 128u;

    for (;;) {
        if (t == 0) wsh = atomicAdd(qctr, 1);
        __syncthreads();
        int w = wsh;
        if (w >= total) break;

        // ---- decode: expert e; (n-tile [, k-chunk]) outer, m-tile inner ----
        int e = 0;
        while (e < NEXP - 1 && w >= wbase[e + 1]) e++;
        w -= wbase[e];
        const int n_e = cnt[e];
        const int ntm = (n_e + 255) >> 8;
        int idx = w / ntm;
        const int mtile = w - idx * ntm;
        int kc = 0;
        if (KSPLIT == 2) { kc = idx & 1; idx >>= 1; }
        const int m0 = mtile * 256;
        const int n0 = idx * BN_;
        const int base = off[e];
        const int k0 = kc * KLEN;

        // ---- staging source pointers (global pre-swizzled: chunk p -> p^(row&7)) ----
        const unsigned short* pA[NA];
        const unsigned short* pB[NB];
#pragma unroll
        for (int i = 0; i < NA; i++) {
            int c = i * 512 + t;
            int row = c >> 3, p = c & 7, cg = p ^ (row & 7);
            int arow = m0 + row; if (arow > n_e - 1) arow = n_e - 1;
            size_t gr = GATHER_A ? (size_t)list[e * TOKENS + arow] : (size_t)(base + arow);
            pA[i] = Abase + gr * (size_t)KD + k0 + cg * 8;
        }
#pragma unroll
        for (int i = 0; i < NB; i++) {
            int c = i * 512 + t;
            int row = c >> 3, p = c & 7, cg = p ^ (row & 7);
            pB[i] = Wt + ((size_t)e * NW + n0 + row) * (size_t)KD + k0 + cg * 8;
        }

        f32x4 acc[8][NF];
#pragma unroll
        for (int i = 0; i < 8; i++)
#pragma unroll
            for (int j = 0; j < NF; j++) acc[i][j] = f32x4{0.f, 0.f, 0.f, 0.f};

        // ---- prologue: stage tile 0 into slot 0 ----
#pragma unroll
        for (int i = 0; i < NA; i++) { GLDS(pA[i], (char*)As[0] + t * 16 + i * 8192); pA[i] += 64; }
#pragma unroll
        for (int i = 0; i < NB; i++) { GLDS(pB[i], (char*)Bs[0] + t * 16 + i * 8192); pB[i] += 64; }
        WAIT_VM0();
        BARRIER();

        const int NT = KLEN >> 6;
        for (int tk = 0; tk < NT; ++tk) {
            const uint32_t coA = (tk & 1) ? SLOTA : 0u;
            const uint32_t coB = (tk & 1) ? SLOTB : 0u;

            // stage next tile FIRST (T3 recipe: loads in flight across the compute)
            if (tk + 1 < NT) {
                char* Ad = (char*)As[(tk & 1) ^ 1];
                char* Bd = (char*)Bs[(tk & 1) ^ 1];
#pragma unroll
                for (int i = 0; i < NA; i++) { GLDS(pA[i], Ad + t * 16 + i * 8192); pA[i] += 64; }
#pragma unroll
                for (int i = 0; i < NB; i++) { GLDS(pB[i], Bd + t * 16 + i * 8192); pB[i] += 64; }
            }

            // two K=32 sub-steps: 12 (or 10) asm ds_reads -> lgkm drain -> MFMA cluster
#pragma unroll
            for (int s = 0; s < 2; s++) {
                const uint32_t cb = (((uint32_t)(s * 64) + g16) ^ swz);
                short8 a[8], b[NF];
#pragma unroll
                for (int mi = 0; mi < 8; mi++) a[mi] = dsr(rA[mi] + coA + cb);
#pragma unroll
                for (int nj = 0; nj < NF; nj++) b[nj] = dsr(rB[nj] + coB + cb);
                WAIT_LGKM0();
                __builtin_amdgcn_sched_barrier(0);   // rule #18
                __builtin_amdgcn_s_setprio(1);
#pragma unroll
                for (int mi = 0; mi < 8; mi++)
#pragma unroll
                    for (int nj = 0; nj < NF; nj++)
                        acc[mi][nj] = __builtin_amdgcn_mfma_f32_16x16x32_bf16(a[mi], b[nj], acc[mi][nj], 0, 0, 0);
                __builtin_amdgcn_s_setprio(0);
            }

            WAIT_VM0();
            BARRIER();
        }

        // ---- epilogue: row = m0 + wm*128 + mi*16 + g*4 + q; col = n0 + wn*WCOL + nj*16 + r16 ----
#pragma unroll
        for (int mi = 0; mi < 8; ++mi) {
#pragma unroll
            for (int nj = 0; nj < NF; ++nj) {
#pragma unroll
                for (int qq = 0; qq < 4; ++qq) {
                    int lr = wm * 128 + mi * 16 + g * 4 + qq;
                    if (m0 + lr < n_e) {
                        int col = n0 + wn * WCOL + nj * 16 + r16;
                        float v = acc[mi][nj][qq];
                        if (SILU) {
                            v = v / (1.f + __expf(-v));
                            Hout[(size_t)(base + m0 + lr) * NW + col] = f2bf(v);
                        } else {
                            int tok = list[e * TOKENS + m0 + lr];
                            atomicAdd(&Yout[(size_t)tok * NW + col], v);
                        }
                    }
                }
            }
        }
    }
}

extern "C" void kernel_launch(void* const* d_in, const int* in_sizes, int n_in,
                              void* d_out, int out_size, void* d_ws, size_t ws_size,
                              hipStream_t stream) {
    const float* X  = (const float*)d_in[0];
    const float* Wr = (const float*)d_in[1];
    const float* W1 = (const float*)d_in[2];
    const float* W2 = (const float*)d_in[3];
    float* Y = (float*)d_out;

    char* ws = (char*)d_ws;
    int* cnt  = (int*)(ws + 0);
    int* off  = (int*)(ws + 64);
    int* wbA  = (int*)(ws + 128);   // 9 ints
    int* wbB  = (int*)(ws + 192);   // 9 ints
    int* qctr = (int*)(ws + 256);   // 2 ints
    int* list = (int*)(ws + 1024);                               // 128 KB
    unsigned short* Xb = (unsigned short*)(ws + (1ull << 20));   // 8 MB
    unsigned short* WT = (unsigned short*)(ws + (16ull << 20));  // 64 MB (W1T, then W2T)
    unsigned short* H  = (unsigned short*)(ws + (80ull << 20));  // 64 MB

    hipMemsetAsync(d_out, 0, (size_t)out_size * sizeof(float), stream);
    hipMemsetAsync(cnt, 0, 32, stream);

    cvt_x<<<TOKENS * DDIM / (256 * 8), 256, 0, stream>>>(X, Xb, TOKENS * DDIM);
    router<<<TOKENS / 4, 256, 0, stream>>>(X, Wr, cnt, list);
    setup<<<1, 64, 0, stream>>>(cnt, off, wbA, wbB, qctr);

    // W1 [E][D][F] -> W1T [E][F][D] bf16
    transpose_cvt<<<dim3(FDIM / 32, DDIM / 32, NEXP), 256, 0, stream>>>(W1, WT, DDIM, FDIM);
    // Pass A: H[slot][F] = silu(X[tok] @ W1[e]); 256x256 tiles, K=1024
    gemm_moe7<256, true, true, 1><<<256, 512, 0, stream>>>(
        Xb, WT, cnt, off, list, wbA, qctr + 0, H, nullptr, DDIM, DDIM, FDIM);

    // W2 [E][F][D] -> W2T [E][D][F] bf16 (reuses WT)
    transpose_cvt<<<dim3(DDIM / 32, FDIM / 32, NEXP), 256, 0, stream>>>(W2, WT, FDIM, DDIM);
    // Pass B: Y[tok][D] += H[slot] @ W2[e]; 256x128 tiles, K split 2x2048
    gemm_moe7<128, false, false, 2><<<256, 512, 0, stream>>>(
        H, WT, cnt, off, list, wbB, qctr + 1, nullptr, Y, FDIM, FDIM / 2, DDIM);
}

// Round 8
// 463.110 us; speedup vs baseline: 3.0488x; 1.0631x over previous
//
#include <hip/hip_runtime.h>
#include <hip/hip_bf16.h>
#include <stdint.h>

#define TOKENS 4096
#define DDIM 1024
#define FDIM 4096
#define NEXP 8
#define BM 128
#define BN 128
#define BK2 32

typedef __attribute__((ext_vector_type(4))) float f32x4;
typedef __attribute__((ext_vector_type(8))) short short8;

__device__ __forceinline__ unsigned short f2bf(float f) {
    union { float f; uint32_t u; } v; v.f = f;
    uint32_t u = v.u;
    return (unsigned short)((u + 0x7fff + ((u >> 16) & 1)) >> 16);
}

#define BARRIER() asm volatile("s_barrier" ::: "memory")
#define WAIT_VM0() asm volatile("s_waitcnt vmcnt(0)" ::: "memory")
#define WAIT_VM4() asm volatile("s_waitcnt vmcnt(4)" ::: "memory")
#define WAIT_LGKM0() asm volatile("s_waitcnt lgkmcnt(0)" ::: "memory")
#define GLDS(SRC, DST) __builtin_amdgcn_global_load_lds( \
    (const __attribute__((address_space(1))) void*)(SRC), \
    (__attribute__((address_space(3))) void*)(DST), 16, 0, 0)

// opaque asm LDS read: explicit waits control all ordering (rule #18 applied at use)
__device__ __forceinline__ short8 dsr(uint32_t addr) {
    short8 d;
    asm volatile("ds_read_b128 %0, %1" : "=v"(d) : "v"(addr));
    return d;
}

// ---------------- X f32 -> bf16 ----------------
__global__ __launch_bounds__(256) void cvt_x(const float* __restrict__ x,
                                             unsigned short* __restrict__ xb, int n) {
    int i = (blockIdx.x * 256 + threadIdx.x) * 8;
    if (i >= n) return;
    float4 a = *(const float4*)(x + i);
    float4 b = *(const float4*)(x + i + 4);
    short8 o;
    o[0] = f2bf(a.x); o[1] = f2bf(a.y); o[2] = f2bf(a.z); o[3] = f2bf(a.w);
    o[4] = f2bf(b.x); o[5] = f2bf(b.y); o[6] = f2bf(b.z); o[7] = f2bf(b.w);
    *(short8*)(xb + i) = o;
}

// ------------- transpose + cvt: in [E][R][C] f32 -> out [E][C][R] bf16 -------------
__global__ __launch_bounds__(256) void transpose_cvt(const float* __restrict__ in,
                                                     unsigned short* __restrict__ out,
                                                     int R, int C) {
    __shared__ float tile[32][33];
    int e = blockIdx.z;
    int r0 = blockIdx.y * 32, c0 = blockIdx.x * 32;
    const float* src = in + (size_t)e * R * C;
    unsigned short* dst = out + (size_t)e * R * C;
    int t = threadIdx.x;
    int rr = t >> 3;
    int cc = (t & 7) * 4;
    float4 v = *(const float4*)(src + (size_t)(r0 + rr) * C + c0 + cc);
    tile[rr][cc + 0] = v.x; tile[rr][cc + 1] = v.y;
    tile[rr][cc + 2] = v.z; tile[rr][cc + 3] = v.w;
    __syncthreads();
    int oc = rr;
    int orr = cc;
    ushort4 o;
    o.x = f2bf(tile[orr + 0][oc]);
    o.y = f2bf(tile[orr + 1][oc]);
    o.z = f2bf(tile[orr + 2][oc]);
    o.w = f2bf(tile[orr + 3][oc]);
    *(ushort4*)(dst + (size_t)(c0 + oc) * R + r0 + orr) = o;
}

// ---------------- router: top-2 of 8 logits, build expert lists ----------------
__global__ __launch_bounds__(256) void router(const float* __restrict__ x,
                                              const float* __restrict__ wr,
                                              int* __restrict__ cnt,
                                              int* __restrict__ list) {
    __shared__ float wl[NEXP * DDIM];
    int t = threadIdx.x;
    for (int i = t; i < NEXP * DDIM; i += 256) wl[i] = wr[i];
    __syncthreads();
    int tok = blockIdx.x * 4 + (t >> 6);
    int lane = t & 63;
    float acc[NEXP];
#pragma unroll
    for (int e = 0; e < NEXP; e++) acc[e] = 0.f;
    const float* xr = x + (size_t)tok * DDIM;
    for (int d = lane; d < DDIM; d += 64) {
        float xv = xr[d];
#pragma unroll
        for (int e = 0; e < NEXP; e++) acc[e] += xv * wl[e * DDIM + d];
    }
#pragma unroll
    for (int e = 0; e < NEXP; e++) {
#pragma unroll
        for (int off = 32; off; off >>= 1) acc[e] += __shfl_xor(acc[e], off);
    }
    if (lane == 0) {
        int e1 = 0; float v1 = acc[0];
        for (int e = 1; e < NEXP; e++) if (acc[e] > v1) { v1 = acc[e]; e1 = e; }
        int e2 = -1; float v2 = -1e30f;
        for (int e = 0; e < NEXP; e++) if (e != e1 && acc[e] > v2) { v2 = acc[e]; e2 = e; }
        int p1 = atomicAdd(&cnt[e1], 1);
        list[e1 * TOKENS + p1] = tok;
        int p2 = atomicAdd(&cnt[e2], 1);
        list[e2 * TOKENS + p2] = tok;
    }
}

// ---------------- setup: offsets, work bases, queue reset ----------------
__global__ void setup(const int* __restrict__ cnt, int* __restrict__ off,
                      int* __restrict__ wbA, int* __restrict__ wbB,
                      int* __restrict__ qctr) {
    if (threadIdx.x == 0) {
        int s = 0, ta = 0, tb = 0;
        for (int e = 0; e < NEXP; e++) {
            off[e] = s; s += cnt[e];
            wbA[e] = ta; wbB[e] = tb;
            int ntm = (cnt[e] + BM - 1) / BM;
            ta += ntm * (FDIM / BN);        // pass A: 32 n-tiles
            tb += ntm * (DDIM / BN) * 2;    // pass B: 8 n-tiles x 2 k-chunks
        }
        wbA[NEXP] = ta; wbB[NEXP] = tb;
        qctr[0] = 0; qctr[1] = 0;
    }
}

// ---------------- persistent grouped GEMM: 128^2, BK=32, 3-slot ring, 3 blk/CU ----------------
// Loop body identical to round-5 (proven): stage-first GLDS -> asm ds_read -> lgkm0 ->
// sched_barrier -> MFMA -> counted vmcnt -> s_barrier. Ring depth 3, prefetch distance 2.
template <bool GATHER_A, bool SILU, int KSPLIT>
__global__ __launch_bounds__(256, 3) void gemm_moe8(
    const unsigned short* __restrict__ Abase,
    const unsigned short* __restrict__ Wt,      // [E][NW][KD] bf16
    const int* __restrict__ cnt, const int* __restrict__ off,
    const int* __restrict__ list,
    const int* __restrict__ wbase,
    int* __restrict__ qctr,
    unsigned short* __restrict__ Hout,          // SILU out, stride NW
    float* __restrict__ Yout,                   // atomic out, stride NW
    int KD, int KLEN, int NW) {
    __shared__ alignas(16) unsigned short As[3][BM * BK2];  // 3 x 8 KB
    __shared__ alignas(16) unsigned short Bs[3][BN * BK2];  // 3 x 8 KB
    __shared__ int wsh;

    const int t = threadIdx.x;
    const int lane = t & 63;
    const int wid = t >> 6;
    const int wm = wid >> 1, wn = wid & 1;
    const int r16 = lane & 15, g = lane >> 4;
    const int total = wbase[NEXP];

    // frag addresses within a slot (slot 0 base); chunk g stored at g^((row>>1)&3)
    const uint32_t asB = (uint32_t)(uintptr_t)&As[0][0];
    const uint32_t bsB = (uint32_t)(uintptr_t)&Bs[0][0];
    uint32_t aAdr[4], bAdr[4];
#pragma unroll
    for (int mi = 0; mi < 4; mi++) {
        int row = wm * 64 + mi * 16 + r16;
        aAdr[mi] = asB + row * 64 + ((g ^ ((row >> 1) & 3)) << 4);
    }
#pragma unroll
    for (int nj = 0; nj < 4; nj++) {
        int row = wn * 64 + nj * 16 + r16;
        bAdr[nj] = bsB + row * 64 + ((g ^ ((row >> 1) & 3)) << 4);
    }

    for (;;) {
        if (t == 0) wsh = atomicAdd(qctr, 1);
        __syncthreads();
        int w = wsh;
        if (w >= total) break;

        // ---- decode: expert e; (n-tile [, k-chunk]) outer, m-tile inner ----
        int e = 0;
        while (e < NEXP - 1 && w >= wbase[e + 1]) e++;
        w -= wbase[e];
        const int n_e = cnt[e];
        const int ntm = (n_e + BM - 1) >> 7;
        int idx = w / ntm;
        const int mtile = w - idx * ntm;
        int kc = 0;
        if (KSPLIT == 2) { kc = idx & 1; idx >>= 1; }
        const int m0 = mtile * BM;
        const int n0 = idx * BN;
        const int base = off[e];
        const int k0 = kc * KLEN;

        // ---- staging pointers: 2 A + 2 B chunks of 16 B per thread per tile ----
        const unsigned short* pA[2];
        const unsigned short* pB[2];
        int ldsOff[2];
#pragma unroll
        for (int i = 0; i < 2; i++) {
            int c = i * 256 + t;
            int row = c >> 2, p = c & 3;
            int cg = p ^ ((row >> 1) & 3);
            int arow = m0 + row; if (arow >= n_e) arow = n_e - 1;
            size_t grow = GATHER_A ? (size_t)list[e * TOKENS + arow] : (size_t)(base + arow);
            pA[i] = Abase + grow * (size_t)KD + k0 + (cg << 3);
            pB[i] = Wt + ((size_t)e * NW + n0 + row) * (size_t)KD + k0 + (cg << 3);
            ldsOff[i] = c * 16;
        }

        f32x4 acc[4][4];
#pragma unroll
        for (int i = 0; i < 4; i++)
#pragma unroll
            for (int j = 0; j < 4; j++) acc[i][j] = f32x4{0.f, 0.f, 0.f, 0.f};

        // ---- prologue: stage tiles 0,1 into slots 0,1 (8 GLDS/thread-pair sets) ----
#pragma unroll
        for (int s = 0; s < 2; ++s) {
#pragma unroll
            for (int i = 0; i < 2; i++) { GLDS(pA[i], (char*)As[s] + ldsOff[i]); pA[i] += BK2; }
#pragma unroll
            for (int i = 0; i < 2; i++) { GLDS(pB[i], (char*)Bs[s] + ldsOff[i]); pB[i] += BK2; }
        }
        WAIT_VM4();   // tile 0 resident; tile 1 still in flight
        BARRIER();

        // rotating ring-slot byte offsets: compute o0, ready o1, stage o2
        uint32_t o0 = 0, o1 = 8192, o2 = 16384;

        const int NT = KLEN / BK2;
        for (int tk = 0; tk < NT; ++tk) {
            // issue stage for tile tk+2 into the slot freed at last barrier
            if (tk + 2 < NT) {
#pragma unroll
                for (int i = 0; i < 2; i++) { GLDS(pA[i], (char*)As[0] + o2 + ldsOff[i]); pA[i] += BK2; }
#pragma unroll
                for (int i = 0; i < 2; i++) { GLDS(pB[i], (char*)Bs[0] + o2 + ldsOff[i]); pB[i] += BK2; }
            }

            // fragment loads: opaque asm ds_read_b128 from compute slot
            short8 a0 = dsr(aAdr[0] + o0);
            short8 a1 = dsr(aAdr[1] + o0);
            short8 a2 = dsr(aAdr[2] + o0);
            short8 a3 = dsr(aAdr[3] + o0);
            short8 b0 = dsr(bAdr[0] + o0);
            short8 b1 = dsr(bAdr[1] + o0);
            short8 b2 = dsr(bAdr[2] + o0);
            short8 b3 = dsr(bAdr[3] + o0);
            WAIT_LGKM0();
            __builtin_amdgcn_sched_barrier(0);   // rule #18

            __builtin_amdgcn_s_setprio(1);
            acc[0][0] = __builtin_amdgcn_mfma_f32_16x16x32_bf16(a0, b0, acc[0][0], 0, 0, 0);
            acc[0][1] = __builtin_amdgcn_mfma_f32_16x16x32_bf16(a0, b1, acc[0][1], 0, 0, 0);
            acc[0][2] = __builtin_amdgcn_mfma_f32_16x16x32_bf16(a0, b2, acc[0][2], 0, 0, 0);
            acc[0][3] = __builtin_amdgcn_mfma_f32_16x16x32_bf16(a0, b3, acc[0][3], 0, 0, 0);
            acc[1][0] = __builtin_amdgcn_mfma_f32_16x16x32_bf16(a1, b0, acc[1][0], 0, 0, 0);
            acc[1][1] = __builtin_amdgcn_mfma_f32_16x16x32_bf16(a1, b1, acc[1][1], 0, 0, 0);
            acc[1][2] = __builtin_amdgcn_mfma_f32_16x16x32_bf16(a1, b2, acc[1][2], 0, 0, 0);
            acc[1][3] = __builtin_amdgcn_mfma_f32_16x16x32_bf16(a1, b3, acc[1][3], 0, 0, 0);
            acc[2][0] = __builtin_amdgcn_mfma_f32_16x16x32_bf16(a2, b0, acc[2][0], 0, 0, 0);
            acc[2][1] = __builtin_amdgcn_mfma_f32_16x16x32_bf16(a2, b1, acc[2][1], 0, 0, 0);
            acc[2][2] = __builtin_amdgcn_mfma_f32_16x16x32_bf16(a2, b2, acc[2][2], 0, 0, 0);
            acc[2][3] = __builtin_amdgcn_mfma_f32_16x16x32_bf16(a2, b3, acc[2][3], 0, 0, 0);
            acc[3][0] = __builtin_amdgcn_mfma_f32_16x16x32_bf16(a3, b0, acc[3][0], 0, 0, 0);
            acc[3][1] = __builtin_amdgcn_mfma_f32_16x16x32_bf16(a3, b1, acc[3][1], 0, 0, 0);
            acc[3][2] = __builtin_amdgcn_mfma_f32_16x16x32_bf16(a3, b2, acc[3][2], 0, 0, 0);
            acc[3][3] = __builtin_amdgcn_mfma_f32_16x16x32_bf16(a3, b3, acc[3][3], 0, 0, 0);
            __builtin_amdgcn_s_setprio(0);

            // counted drain: tile tk+1 must be resident; tk+2's 4 loads stay in flight
            if (tk + 1 < NT) {
                if (tk + 2 < NT) WAIT_VM4();
                else             WAIT_VM0();
                BARRIER();
            }
            uint32_t tmp = o0; o0 = o1; o1 = o2; o2 = tmp;
        }

        // ---- epilogue: row = m0+wm*64+mi*16+g*4+q; col = n0+wn*64+nj*16+r16 ----
#pragma unroll
        for (int mi = 0; mi < 4; ++mi) {
#pragma unroll
            for (int nj = 0; nj < 4; ++nj) {
#pragma unroll
                for (int qq = 0; qq < 4; ++qq) {
                    int lr = wm * 64 + mi * 16 + g * 4 + qq;
                    if (m0 + lr < n_e) {
                        int col = n0 + wn * 64 + nj * 16 + r16;
                        float v = acc[mi][nj][qq];
                        if (SILU) {
                            v = v / (1.f + __expf(-v));
                            Hout[(size_t)(base + m0 + lr) * NW + col] = f2bf(v);
                        } else {
                            int tok = list[e * TOKENS + m0 + lr];
                            atomicAdd(&Yout[(size_t)tok * NW + col], v);
                        }
                    }
                }
            }
        }
    }
}

extern "C" void kernel_launch(void* const* d_in, const int* in_sizes, int n_in,
                              void* d_out, int out_size, void* d_ws, size_t ws_size,
                              hipStream_t stream) {
    const float* X  = (const float*)d_in[0];
    const float* Wr = (const float*)d_in[1];
    const float* W1 = (const float*)d_in[2];
    const float* W2 = (const float*)d_in[3];
    float* Y = (float*)d_out;

    char* ws = (char*)d_ws;
    int* cnt  = (int*)(ws + 0);
    int* off  = (int*)(ws + 64);
    int* wbA  = (int*)(ws + 128);
    int* wbB  = (int*)(ws + 192);
    int* qctr = (int*)(ws + 256);
    int* list = (int*)(ws + 1024);                               // 128 KB
    unsigned short* Xb = (unsigned short*)(ws + (1ull << 20));   // 8 MB
    unsigned short* WT = (unsigned short*)(ws + (16ull << 20));  // 64 MB (W1T, then W2T)
    unsigned short* H  = (unsigned short*)(ws + (80ull << 20));  // 64 MB

    hipMemsetAsync(d_out, 0, (size_t)out_size * sizeof(float), stream);
    hipMemsetAsync(cnt, 0, 32, stream);

    cvt_x<<<TOKENS * DDIM / (256 * 8), 256, 0, stream>>>(X, Xb, TOKENS * DDIM);
    router<<<TOKENS / 4, 256, 0, stream>>>(X, Wr, cnt, list);
    setup<<<1, 64, 0, stream>>>(cnt, off, wbA, wbB, qctr);

    // W1 [E][D][F] -> W1T [E][F][D] bf16
    transpose_cvt<<<dim3(FDIM / 32, DDIM / 32, NEXP), 256, 0, stream>>>(W1, WT, DDIM, FDIM);
    // Pass A: H[slot][F] = silu(X[tok] @ W1[e]); K=1024
    gemm_moe8<true, true, 1><<<768, 256, 0, stream>>>(
        Xb, WT, cnt, off, list, wbA, qctr + 0, H, nullptr, DDIM, DDIM, FDIM);

    // W2 [E][F][D] -> W2T [E][D][F] bf16 (reuses WT)
    transpose_cvt<<<dim3(DDIM / 32, FDIM / 32, NEXP), 256, 0, stream>>>(W2, WT, FDIM, DDIM);
    // Pass B: Y[tok][D] += H[slot] @ W2[e]; K split 2 x 2048
    gemm_moe8<false, false, 2><<<768, 256, 0, stream>>>(
        H, WT, cnt, off, list, wbB, qctr + 1, nullptr, Y, FDIM, FDIM / 2, DDIM);
}